// Round 4
// baseline (419.000 us; speedup 1.0000x reference)
//
#include <hip/hip_runtime.h>
#include <hip/hip_bf16.h>
#include <cstdint>
#include <cstddef>

#define B_ 2
#define S_ 2048
#define D_ 2048
#define H_ 16
#define HD_ 128

typedef __bf16 bf16_t;
typedef __bf16 bf16x8 __attribute__((ext_vector_type(8)));
typedef __bf16 bf16x4 __attribute__((ext_vector_type(4)));
typedef short s16x4 __attribute__((ext_vector_type(4)));
typedef float f32x4 __attribute__((ext_vector_type(4)));

__device__ __forceinline__ void async16(const bf16_t* g, bf16_t* l) {
    __builtin_amdgcn_global_load_lds(
        (const __attribute__((address_space(1))) unsigned int*)g,
        (__attribute__((address_space(3))) unsigned int*)l, 16, 0, 0);
}

// K=16 bf16 MFMA with builtin-name portability chain
__device__ __forceinline__ f32x4 mfma16x16x16_bf16(bf16x4 a, bf16x4 b, f32x4 c) {
#if __has_builtin(__builtin_amdgcn_mfma_f32_16x16x16_bf16)
    return __builtin_amdgcn_mfma_f32_16x16x16_bf16(a, b, c, 0, 0, 0);
#elif __has_builtin(__builtin_amdgcn_mfma_f32_16x16x16bf16_1k)
    return __builtin_amdgcn_mfma_f32_16x16x16bf16_1k(
        __builtin_bit_cast(s16x4, a), __builtin_bit_cast(s16x4, b), c, 0, 0, 0);
#else
    f32x4 d = c;
    asm("v_mfma_f32_16x16x16_bf16 %0, %1, %2, %0" : "+v"(d) : "v"(a), "v"(b));
    return d;
#endif
}

// ---------------- fused fp32 -> bf16 convert; Wq gets 1/sqrt(HD) folded in ----------------
__global__ void f2b_multi(const float* __restrict__ x, const float* __restrict__ wq,
                          const float* __restrict__ wk, const float* __restrict__ wv,
                          const float* __restrict__ wo, bf16_t* __restrict__ xb,
                          bf16_t* __restrict__ wqb, bf16_t* __restrict__ wkb,
                          bf16_t* __restrict__ wvb, bf16_t* __restrict__ wob) {
    const float* in; bf16_t* out;
    float sc = 1.0f;
    switch (blockIdx.y) {
        case 0: in = x;            out = xb;            break;
        case 1: in = x + 4194304;  out = xb + 4194304;  break;
        case 2: in = wq;           out = wqb; sc = 0.08838834764831845f; break;
        case 3: in = wk;           out = wkb;           break;
        case 4: in = wv;           out = wvb;           break;
        default: in = wo;          out = wob;           break;
    }
    int i = (blockIdx.x * blockDim.x + threadIdx.x) * 4;
    float4 v = *(const float4*)(in + i);
    bf16x4 o = { (bf16_t)(v.x * sc), (bf16_t)(v.y * sc), (bf16_t)(v.z * sc), (bf16_t)(v.w * sc) };
    *(bf16x4*)(out + i) = o;
}

// ---------------- RoPE cos/sin table: tab[s][j] = (cos, sin) of s * 10000^(-j/64) ----------------
__global__ void rope_tab(float2* __restrict__ tab) {
    int idx = blockIdx.x * blockDim.x + threadIdx.x;  // [0, 2048*64)
    int s = idx >> 6, j = idx & 63;
    float inv = __expf(-(float)j * 0.14391156831212787f);
    float ang = (float)s * inv;
    float sn, c;
    __sincosf(ang, &sn, &c);
    tab[idx] = make_float2(c, sn);
}

// ---------------- fused QKV GEMM: [q|k|v] = x @ W^T; RoPE fused for q,k; V transposed ----------------
// grid (48, 32): seg = bx/16 (0=q,1=k,2=v). Wave's B-fragments remapped to cols
// {16W + 32ns + lo} so each thread holds both halves of each RoPE pair (j, j+64).
__global__ __launch_bounds__(256) void gemm_qkv(const bf16_t* __restrict__ A,
                                                const bf16_t* __restrict__ Wq,
                                                const bf16_t* __restrict__ Wk,
                                                const bf16_t* __restrict__ Wv,
                                                const float2* __restrict__ tab,
                                                bf16_t* __restrict__ qb,
                                                bf16_t* __restrict__ kb,
                                                bf16_t* __restrict__ vtb) {
    __shared__ __align__(16) bf16_t As[128 * 32];
    __shared__ __align__(16) bf16_t Bs[128 * 32];
    const int K = D_;
    int t = threadIdx.x;
    int w = t >> 6, lane = t & 63, lo = lane & 15, hi = lane >> 4;
    int seg = blockIdx.x >> 4;
    int n0 = (blockIdx.x & 15) * 128;
    int m0 = blockIdx.y * 128;
    const bf16_t* Bt = (seg == 0) ? Wq : (seg == 1) ? Wk : Wv;
    int wm = (w & 1) * 64, W = (w >> 1);
    f32x4 acc[4][4] = {};
    const bf16_t* ga = A + (size_t)(m0 + (t >> 2)) * K + (t & 3) * 8;
    const bf16_t* gb = Bt + (size_t)(n0 + (t >> 2)) * K + (t & 3) * 8;
    for (int k0 = 0; k0 < K; k0 += 32) {
        async16(ga + k0,                  As + t * 8);
        async16(ga + (size_t)64 * K + k0, As + 2048 + t * 8);
        async16(gb + k0,                  Bs + t * 8);
        async16(gb + (size_t)64 * K + k0, Bs + 2048 + t * 8);
        __syncthreads();
        bf16x8 af[4], bfr[4];
#pragma unroll
        for (int ms = 0; ms < 4; ++ms)
            af[ms] = *(const bf16x8*)(As + (wm + ms * 16 + lo) * 32 + hi * 8);
#pragma unroll
        for (int ns = 0; ns < 4; ++ns)
            bfr[ns] = *(const bf16x8*)(Bs + (W * 16 + ns * 32 + lo) * 32 + hi * 8);
#pragma unroll
        for (int ms = 0; ms < 4; ++ms)
#pragma unroll
            for (int ns = 0; ns < 4; ++ns)
                acc[ms][ns] = __builtin_amdgcn_mfma_f32_16x16x32_bf16(af[ms], bfr[ns], acc[ms][ns], 0, 0, 0);
        __syncthreads();
    }
    if (seg < 2) {
        // RoPE fused epilogue: col(ns) = n0 + 16W + 32ns + lo; pairs (ns, ns+2) are 64 apart
        bf16_t* C = (seg == 0) ? qb : kb;
        int j0 = W * 16 + lo;
#pragma unroll
        for (int ms = 0; ms < 4; ++ms) {
            int mbase = m0 + wm + ms * 16 + hi * 4;
#pragma unroll
            for (int r = 0; r < 4; ++r) {
                int m = mbase + r;
                int s = m & (S_ - 1);
                const float2* trow = tab + s * 64;
#pragma unroll
                for (int ns = 0; ns < 2; ++ns) {
                    int j = j0 + ns * 32;
                    float2 cs = trow[j];
                    float v0 = acc[ms][ns][r], v1 = acc[ms][ns + 2][r];
                    C[(size_t)m * D_ + n0 + j]      = (bf16_t)(v0 * cs.x - v1 * cs.y);
                    C[(size_t)m * D_ + n0 + j + 64] = (bf16_t)(v1 * cs.x + v0 * cs.y);
                }
            }
        }
    } else {
        // V transposed: vtb[b][d][s]
#pragma unroll
        for (int ms = 0; ms < 4; ++ms) {
            int mrow = m0 + wm + ms * 16 + hi * 4;
            int bb = mrow >> 11, s = mrow & (S_ - 1);
#pragma unroll
            for (int ns = 0; ns < 4; ++ns) {
                int d = n0 + W * 16 + ns * 32 + lo;
                bf16x4 pv = { (bf16_t)acc[ms][ns][0], (bf16_t)acc[ms][ns][1],
                              (bf16_t)acc[ms][ns][2], (bf16_t)acc[ms][ns][3] };
                *(bf16x4*)(vtb + (size_t)bb * D_ * S_ + (size_t)d * S_ + s) = pv;
            }
        }
    }
}

// ---------------- GEMM: C[M,N] = A[M,K] * Bt[N,K]^T, fp32 out (final proj) ----------------
__global__ __launch_bounds__(256) void gemm_bt_f32(const bf16_t* __restrict__ A,
                                                   const bf16_t* __restrict__ Bt,
                                                   float* __restrict__ C,
                                                   int M, int N, int K) {
    __shared__ __align__(16) bf16_t As[128 * 32];
    __shared__ __align__(16) bf16_t Bs[128 * 32];
    int t = threadIdx.x;
    int w = t >> 6, lane = t & 63, lo = lane & 15, hi = lane >> 4;
    int m0 = blockIdx.y * 128, n0 = blockIdx.x * 128;
    int wm = (w & 1) * 64, wn = (w >> 1) * 64;
    f32x4 acc[4][4] = {};
    const bf16_t* ga = A + (size_t)(m0 + (t >> 2)) * K + (t & 3) * 8;
    const bf16_t* gb = Bt + (size_t)(n0 + (t >> 2)) * K + (t & 3) * 8;
    for (int k0 = 0; k0 < K; k0 += 32) {
        async16(ga + k0,                  As + t * 8);
        async16(ga + (size_t)64 * K + k0, As + 2048 + t * 8);
        async16(gb + k0,                  Bs + t * 8);
        async16(gb + (size_t)64 * K + k0, Bs + 2048 + t * 8);
        __syncthreads();
        bf16x8 af[4], bfr[4];
#pragma unroll
        for (int ms = 0; ms < 4; ++ms)
            af[ms] = *(const bf16x8*)(As + (wm + ms * 16 + lo) * 32 + hi * 8);
#pragma unroll
        for (int ns = 0; ns < 4; ++ns)
            bfr[ns] = *(const bf16x8*)(Bs + (wn + ns * 16 + lo) * 32 + hi * 8);
#pragma unroll
        for (int ms = 0; ms < 4; ++ms)
#pragma unroll
            for (int ns = 0; ns < 4; ++ns)
                acc[ms][ns] = __builtin_amdgcn_mfma_f32_16x16x32_bf16(af[ms], bfr[ns], acc[ms][ns], 0, 0, 0);
        __syncthreads();
    }
#pragma unroll
    for (int ms = 0; ms < 4; ++ms)
#pragma unroll
        for (int ns = 0; ns < 4; ++ns)
#pragma unroll
            for (int r = 0; r < 4; ++r)
                C[(size_t)(m0 + wm + ms * 16 + hi * 4 + r) * N + n0 + wn + ns * 16 + lo] = acc[ms][ns][r];
}

// ---------------- Flash attention v4: BK=128 (half the barriers), S^T trick ----------------
// grid (16, 32), 256 thr = 4 waves. Block does q-subtiles bx and 31-bx (64 rows each);
// k-tiles are 128 wide -> floor(bx/2)+floor((31-bx)/2)+2 = 17 tiles/block for all bx.
__global__ __launch_bounds__(256) void attn_kernel(const bf16_t* __restrict__ q,
                                                   const bf16_t* __restrict__ k,
                                                   const bf16_t* __restrict__ vt,
                                                   bf16_t* __restrict__ o) {
    __shared__ __align__(16) bf16_t Ks[128 * 128];  // 32 KB [krow][d], 16-chunk swz ^ (row&15)
    __shared__ __align__(16) bf16_t Vs[128 * 128];  // 32 KB [d][kk],  16-chunk swz ^ (d&15)
    int t = threadIdx.x;
    int w = t >> 6, lane = t & 63, lo = lane & 15, hi = lane >> 4;
    int bx = blockIdx.x;
    int b = blockIdx.y >> 4, h = blockIdx.y & 15;
    const size_t head_off = (size_t)b * S_ * D_ + (size_t)h * HD_;
    const size_t vhead_off = ((size_t)b * D_ + (size_t)h * HD_) * S_;

#pragma unroll 1
    for (int pass = 0; pass < 2; ++pass) {
        int qt = pass ? (31 - bx) : bx;   // 64-row q-subtile index
        int q0 = qt * 64;
        int qg = q0 + w * 16 + lo;        // this lane's q row (lane dim = q)
        bf16x8 aq[4];
#pragma unroll
        for (int c = 0; c < 4; ++c)
            aq[c] = *(const bf16x8*)(q + head_off + (size_t)qg * D_ + c * 32 + hi * 8);

        float l_part = 0.f;
        f32x4 oacc[8] = {};
        int nkt = (qt >> 1) + 1;
        for (int kt = 0; kt < nkt; ++kt) {
            int k0 = kt * 128;
            __syncthreads();  // prior compute's LDS reads done
            // stage K tile (128 x 128): 32 chunks of 1KB, wave w does 8
#pragma unroll
            for (int i = 0; i < 8; ++i) {
                int chunk = w * 8 + i;
                int r = chunk * 4 + (lane >> 4);
                int lc = (lane & 15) ^ (r & 15);
                async16(k + head_off + (size_t)(k0 + r) * D_ + lc * 8,
                        Ks + chunk * 512 + lane * 8);
            }
            // stage V^T tile (128 d x 128 kk): 32 chunks, wave w does 8
#pragma unroll
            for (int i = 0; i < 8; ++i) {
                int chunk = w * 8 + i;
                int d = chunk * 4 + (lane >> 4);
                int lc = (lane & 15) ^ (d & 15);
                async16(vt + vhead_off + (size_t)d * S_ + k0 + lc * 8,
                        Vs + chunk * 512 + lane * 8);
            }
            __syncthreads();  // staging visible

            if (k0 <= q0 + w * 16 + 15) {  // wave-uniform: skip fully-masked tiles
                // S^T = K * Q^T : C cols = q (lo), C rows = k (nt*16 + hi*4 + r)
                f32x4 sacc[8] = {};
#pragma unroll
                for (int c = 0; c < 4; ++c) {
#pragma unroll
                    for (int nt = 0; nt < 8; ++nt) {
                        int row = nt * 16 + lo;
                        int pc = (c * 4 + hi) ^ lo;
                        bf16x8 ak = *(const bf16x8*)(Ks + row * 128 + pc * 8);
                        sacc[nt] = __builtin_amdgcn_mfma_f32_16x16x32_bf16(ak, aq[c], sacc[nt], 0, 0, 0);
                    }
                }
                bool diag = (k0 + 127 > q0 + w * 16);
                bf16x4 pf[8];
#pragma unroll
                for (int nt = 0; nt < 8; ++nt) {
#pragma unroll
                    for (int r = 0; r < 4; ++r) {
                        float e = __expf(fminf(sacc[nt][r], 60.f));
                        if (diag) {
                            int kg = k0 + nt * 16 + hi * 4 + r;
                            if (kg > qg) e = 0.f;
                        }
                        l_part += e;
                        pf[nt][r] = (bf16_t)e;
                    }
                }
                // O^T[d][q] += V^T * P^T  (x16 MFMA: both operands' k = hi*4+j)
#pragma unroll
                for (int nt = 0; nt < 8; ++nt) {
                    int kkb = nt * 16 + hi * 4;
                    int c16 = kkb >> 3, rem = kkb & 7;
#pragma unroll
                    for (int dt = 0; dt < 8; ++dt) {
                        int d = dt * 16 + lo;
                        bf16x4 av = *(const bf16x4*)(Vs + d * 128 + (c16 ^ (d & 15)) * 8 + rem);
                        oacc[dt] = mfma16x16x16_bf16(av, pf[nt], oacc[dt]);
                    }
                }
            }
        }
        // epilogue: reduce l over hi-groups (q = lo is lane-resident), write O^T
        float l = l_part;
        l += __shfl_xor(l, 16);
        l += __shfl_xor(l, 32);
        float rl = 1.0f / l;
#pragma unroll
        for (int dt = 0; dt < 8; ++dt) {
            bf16x4 ov = { (bf16_t)(oacc[dt][0] * rl), (bf16_t)(oacc[dt][1] * rl),
                          (bf16_t)(oacc[dt][2] * rl), (bf16_t)(oacc[dt][3] * rl) };
            *(bf16x4*)(o + head_off + (size_t)qg * D_ + dt * 16 + hi * 4) = ov;
        }
    }
}

// ---------------- launch ----------------
extern "C" void kernel_launch(void* const* d_in, const int* in_sizes, int n_in,
                              void* d_out, int out_size, void* d_ws, size_t ws_size,
                              hipStream_t stream) {
    (void)in_sizes; (void)n_in; (void)out_size; (void)ws_size;
    const float* x  = (const float*)d_in[0];
    const float* Wq = (const float*)d_in[1];
    const float* Wk = (const float*)d_in[2];
    const float* Wv = (const float*)d_in[3];
    const float* Wo = (const float*)d_in[4];
    char* ws = (char*)d_ws;
    bf16_t* xb  = (bf16_t*)(ws);
    bf16_t* Wqb = (bf16_t*)(ws + 16777216);
    bf16_t* Wkb = (bf16_t*)(ws + 25165824);
    bf16_t* Wvb = (bf16_t*)(ws + 33554432);
    bf16_t* Wob = (bf16_t*)(ws + 41943040);
    bf16_t* qb  = (bf16_t*)(ws + 50331648);
    bf16_t* kb  = (bf16_t*)(ws + 67108864);
    bf16_t* vtb = (bf16_t*)(ws + 83886080);
    bf16_t* ob  = (bf16_t*)(ws + 100663296);
    // RoPE table lives in ob's region: consumed by gemm_qkv, dead before attn writes ob.
    float2* tab = (float2*)(ws + 100663296);
    float* out = (float*)d_out;

    rope_tab<<<512, 256, 0, stream>>>(tab);
    f2b_multi<<<dim3(4096, 6), 256, 0, stream>>>(x, Wq, Wk, Wv, Wo, xb, Wqb, Wkb, Wvb, Wob);

    gemm_qkv<<<dim3(48, 32), 256, 0, stream>>>(xb, Wqb, Wkb, Wvb, tab, qb, kb, vtb);

    attn_kernel<<<dim3(16, B_ * H_), 256, 0, stream>>>(qb, kb, vtb, ob);

    gemm_bt_f32<<<dim3(D_ / 128, (B_ * S_) / 128), 256, 0, stream>>>(ob, Wob, out, B_ * S_, D_, D_);
}

// Round 5
// 382.191 us; speedup vs baseline: 1.0963x; 1.0963x over previous
//
#include <hip/hip_runtime.h>
#include <hip/hip_bf16.h>
#include <cstdint>
#include <cstddef>

#define B_ 2
#define S_ 2048
#define D_ 2048
#define H_ 16
#define HD_ 128

typedef __bf16 bf16_t;
typedef __bf16 bf16x8 __attribute__((ext_vector_type(8)));
typedef __bf16 bf16x4 __attribute__((ext_vector_type(4)));
typedef short s16x4 __attribute__((ext_vector_type(4)));
typedef float f32x4 __attribute__((ext_vector_type(4)));

__device__ __forceinline__ void async16(const bf16_t* g, bf16_t* l) {
    __builtin_amdgcn_global_load_lds(
        (const __attribute__((address_space(1))) unsigned int*)g,
        (__attribute__((address_space(3))) unsigned int*)l, 16, 0, 0);
}

// K=16 bf16 MFMA with builtin-name portability chain
__device__ __forceinline__ f32x4 mfma16x16x16_bf16(bf16x4 a, bf16x4 b, f32x4 c) {
#if __has_builtin(__builtin_amdgcn_mfma_f32_16x16x16_bf16)
    return __builtin_amdgcn_mfma_f32_16x16x16_bf16(a, b, c, 0, 0, 0);
#elif __has_builtin(__builtin_amdgcn_mfma_f32_16x16x16bf16_1k)
    return __builtin_amdgcn_mfma_f32_16x16x16bf16_1k(
        __builtin_bit_cast(s16x4, a), __builtin_bit_cast(s16x4, b), c, 0, 0, 0);
#else
    f32x4 d = c;
    asm("v_mfma_f32_16x16x16_bf16 %0, %1, %2, %0" : "+v"(d) : "v"(a), "v"(b));
    return d;
#endif
}

// ---------------- fused fp32 -> bf16 convert; Wq gets 1/sqrt(HD) folded in ----------------
__global__ void f2b_multi(const float* __restrict__ x, const float* __restrict__ wq,
                          const float* __restrict__ wk, const float* __restrict__ wv,
                          const float* __restrict__ wo, bf16_t* __restrict__ xb,
                          bf16_t* __restrict__ wqb, bf16_t* __restrict__ wkb,
                          bf16_t* __restrict__ wvb, bf16_t* __restrict__ wob) {
    const float* in; bf16_t* out;
    float sc = 1.0f;
    switch (blockIdx.y) {
        case 0: in = x;            out = xb;            break;
        case 1: in = x + 4194304;  out = xb + 4194304;  break;
        case 2: in = wq;           out = wqb; sc = 0.08838834764831845f; break;
        case 3: in = wk;           out = wkb;           break;
        case 4: in = wv;           out = wvb;           break;
        default: in = wo;          out = wob;           break;
    }
    int i = (blockIdx.x * blockDim.x + threadIdx.x) * 4;
    float4 v = *(const float4*)(in + i);
    bf16x4 o = { (bf16_t)(v.x * sc), (bf16_t)(v.y * sc), (bf16_t)(v.z * sc), (bf16_t)(v.w * sc) };
    *(bf16x4*)(out + i) = o;
}

// ---------------- RoPE (in-place, x8 vectorized); scale already folded into Wq ----------------
__global__ void rope_kernel(bf16_t* __restrict__ q, bf16_t* __restrict__ k) {
    int idx = blockIdx.x * blockDim.x + threadIdx.x;  // [0, B*S*H*8)
    bf16_t* p = (blockIdx.y == 0) ? q : k;
    int i0 = (idx & 7) * 8;
    int rest = idx >> 3;
    int h = rest & (H_ - 1);
    int row = rest >> 4;
    int s = row & (S_ - 1);
    size_t base = (size_t)row * D_ + (size_t)h * HD_ + i0;
    bf16x8 x0 = *(bf16x8*)(p + base);
    bf16x8 x1 = *(bf16x8*)(p + base + 64);
    bf16x8 o0, o1;
#pragma unroll
    for (int j = 0; j < 8; ++j) {
        float inv = __expf(-(float)(i0 + j) * 0.14391156831212787f);
        float ang = (float)s * inv;
        float sn, c;
        __sincosf(ang, &sn, &c);
        float a = (float)x0[j], bb = (float)x1[j];
        o0[j] = (bf16_t)(a * c - bb * sn);
        o1[j] = (bf16_t)(bb * c + a * sn);
    }
    *(bf16x8*)(p + base) = o0;
    *(bf16x8*)(p + base + 64) = o1;
}

// =====================================================================================
// BK=64 GEMM core layout: As/Bs are [128 rows][64 elems]; a row = 128 B = all 32 banks,
// stored as 8 chunks of 16 B with physical chunk = logical_chunk ^ (row & 7).
// -> every b128 fragment read covers all 32 banks at exactly 2-way aliasing (free),
//    vs the m97 64-B-row layout's 8-way conflicts (measured 1.26e7 SQ_LDS_BANK_CONFLICT).
// Staging: wave w owns rows [w*32, w*32+32); lane l -> row w*32+i*8+(l>>3),
// phys chunk l&7, logical chunk (l&7)^(l>>3); LDS dest = uniform base + l*16 (async16-legal).
// =====================================================================================

// ---------------- fused QKV GEMM: [q|k|v] = x @ W^T; V written transposed ----------------
// grid (48, 32): seg = bx/16 (0=q,1=k,2=v), 256 thr.
__global__ __launch_bounds__(256) void gemm_qkv(const bf16_t* __restrict__ A,
                                                const bf16_t* __restrict__ Wq,
                                                const bf16_t* __restrict__ Wk,
                                                const bf16_t* __restrict__ Wv,
                                                bf16_t* __restrict__ qb,
                                                bf16_t* __restrict__ kb,
                                                bf16_t* __restrict__ vtb) {
    __shared__ __align__(16) bf16_t As[128 * 64];
    __shared__ __align__(16) bf16_t Bs[128 * 64];
    const int K = D_;
    int t = threadIdx.x;
    int w = t >> 6, lane = t & 63, lo = lane & 15, hi = lane >> 4;
    int seg = blockIdx.x >> 4;
    int n0 = (blockIdx.x & 15) * 128;
    int m0 = blockIdx.y * 128;
    const bf16_t* Bt = (seg == 0) ? Wq : (seg == 1) ? Wk : Wv;
    int wm = (w & 1) * 64, wn = (w >> 1) * 64;
    f32x4 acc[4][4] = {};
    int srow = w * 32 + (lane >> 3);
    int scol = ((lane & 7) ^ (lane >> 3)) * 8;
    const bf16_t* gA = A  + (size_t)(m0 + srow) * K + scol;
    const bf16_t* gB = Bt + (size_t)(n0 + srow) * K + scol;
    bf16_t* lA = As + w * 2048 + lane * 8;
    bf16_t* lB = Bs + w * 2048 + lane * 8;
    for (int k0 = 0; k0 < K; k0 += 64) {
#pragma unroll
        for (int i = 0; i < 4; ++i) {
            async16(gA + (size_t)(i * 8) * K + k0, lA + i * 512);
            async16(gB + (size_t)(i * 8) * K + k0, lB + i * 512);
        }
        __syncthreads();
#pragma unroll
        for (int kk = 0; kk < 2; ++kk) {
            bf16x8 af[4], bfr[4];
            int pc = (kk * 4 + hi) ^ (lo & 7);
#pragma unroll
            for (int ms = 0; ms < 4; ++ms)
                af[ms] = *(const bf16x8*)(As + (wm + ms * 16 + lo) * 64 + pc * 8);
#pragma unroll
            for (int ns = 0; ns < 4; ++ns)
                bfr[ns] = *(const bf16x8*)(Bs + (wn + ns * 16 + lo) * 64 + pc * 8);
#pragma unroll
            for (int ms = 0; ms < 4; ++ms)
#pragma unroll
                for (int ns = 0; ns < 4; ++ns)
                    acc[ms][ns] = __builtin_amdgcn_mfma_f32_16x16x32_bf16(af[ms], bfr[ns], acc[ms][ns], 0, 0, 0);
        }
        __syncthreads();
    }
    if (seg < 2) {
        bf16_t* C = (seg == 0) ? qb : kb;
#pragma unroll
        for (int ms = 0; ms < 4; ++ms)
#pragma unroll
            for (int ns = 0; ns < 4; ++ns)
#pragma unroll
                for (int r = 0; r < 4; ++r)
                    C[(size_t)(m0 + wm + ms * 16 + hi * 4 + r) * D_ + n0 + wn + ns * 16 + lo] = (bf16_t)acc[ms][ns][r];
    } else {
        // V transposed: vtb[b][d][s]
#pragma unroll
        for (int ms = 0; ms < 4; ++ms) {
            int mrow = m0 + wm + ms * 16 + hi * 4;
            int bb = mrow >> 11, s = mrow & (S_ - 1);
#pragma unroll
            for (int ns = 0; ns < 4; ++ns) {
                int d = n0 + wn + ns * 16 + lo;
                bf16x4 pv = { (bf16_t)acc[ms][ns][0], (bf16_t)acc[ms][ns][1],
                              (bf16_t)acc[ms][ns][2], (bf16_t)acc[ms][ns][3] };
                *(bf16x4*)(vtb + (size_t)bb * D_ * S_ + (size_t)d * S_ + s) = pv;
            }
        }
    }
}

// ---------------- GEMM: C[M,N] = A[M,K] * Bt[N,K]^T, fp32 out (final proj) ----------------
__global__ __launch_bounds__(256) void gemm_bt_f32(const bf16_t* __restrict__ A,
                                                   const bf16_t* __restrict__ Bt,
                                                   float* __restrict__ C,
                                                   int M, int N, int K) {
    __shared__ __align__(16) bf16_t As[128 * 64];
    __shared__ __align__(16) bf16_t Bs[128 * 64];
    int t = threadIdx.x;
    int w = t >> 6, lane = t & 63, lo = lane & 15, hi = lane >> 4;
    int m0 = blockIdx.y * 128, n0 = blockIdx.x * 128;
    int wm = (w & 1) * 64, wn = (w >> 1) * 64;
    f32x4 acc[4][4] = {};
    int srow = w * 32 + (lane >> 3);
    int scol = ((lane & 7) ^ (lane >> 3)) * 8;
    const bf16_t* gA = A  + (size_t)(m0 + srow) * K + scol;
    const bf16_t* gB = Bt + (size_t)(n0 + srow) * K + scol;
    bf16_t* lA = As + w * 2048 + lane * 8;
    bf16_t* lB = Bs + w * 2048 + lane * 8;
    for (int k0 = 0; k0 < K; k0 += 64) {
#pragma unroll
        for (int i = 0; i < 4; ++i) {
            async16(gA + (size_t)(i * 8) * K + k0, lA + i * 512);
            async16(gB + (size_t)(i * 8) * K + k0, lB + i * 512);
        }
        __syncthreads();
#pragma unroll
        for (int kk = 0; kk < 2; ++kk) {
            bf16x8 af[4], bfr[4];
            int pc = (kk * 4 + hi) ^ (lo & 7);
#pragma unroll
            for (int ms = 0; ms < 4; ++ms)
                af[ms] = *(const bf16x8*)(As + (wm + ms * 16 + lo) * 64 + pc * 8);
#pragma unroll
            for (int ns = 0; ns < 4; ++ns)
                bfr[ns] = *(const bf16x8*)(Bs + (wn + ns * 16 + lo) * 64 + pc * 8);
#pragma unroll
            for (int ms = 0; ms < 4; ++ms)
#pragma unroll
                for (int ns = 0; ns < 4; ++ns)
                    acc[ms][ns] = __builtin_amdgcn_mfma_f32_16x16x32_bf16(af[ms], bfr[ns], acc[ms][ns], 0, 0, 0);
        }
        __syncthreads();
    }
#pragma unroll
    for (int ms = 0; ms < 4; ++ms)
#pragma unroll
        for (int ns = 0; ns < 4; ++ns)
#pragma unroll
            for (int r = 0; r < 4; ++r)
                C[(size_t)(m0 + wm + ms * 16 + hi * 4 + r) * N + n0 + wn + ns * 16 + lo] = acc[ms][ns][r];
}

// ---------------- Flash attention v4: BK=128, S^T trick, no-max softmax, P in-register ----------------
// grid (16, 32), 256 thr = 4 waves. Block does q-subtiles bx and 31-bx (64 rows each);
// 128-wide k-tiles -> floor(bx/2)+floor((31-bx)/2)+2 = 17 tiles/block for all bx.
__global__ __launch_bounds__(256) void attn_kernel(const bf16_t* __restrict__ q,
                                                   const bf16_t* __restrict__ k,
                                                   const bf16_t* __restrict__ vt,
                                                   bf16_t* __restrict__ o) {
    __shared__ __align__(16) bf16_t Ks[128 * 128];  // 32 KB [krow][d], 16-chunk swz ^ (row&15)
    __shared__ __align__(16) bf16_t Vs[128 * 128];  // 32 KB [d][kk],  16-chunk swz ^ (d&15)
    int t = threadIdx.x;
    int w = t >> 6, lane = t & 63, lo = lane & 15, hi = lane >> 4;
    int bx = blockIdx.x;
    int b = blockIdx.y >> 4, h = blockIdx.y & 15;
    const size_t head_off = (size_t)b * S_ * D_ + (size_t)h * HD_;
    const size_t vhead_off = ((size_t)b * D_ + (size_t)h * HD_) * S_;

#pragma unroll 1
    for (int pass = 0; pass < 2; ++pass) {
        int qt = pass ? (31 - bx) : bx;   // 64-row q-subtile index
        int q0 = qt * 64;
        int qg = q0 + w * 16 + lo;        // this lane's q row (lane dim = q)
        bf16x8 aq[4];
#pragma unroll
        for (int c = 0; c < 4; ++c)
            aq[c] = *(const bf16x8*)(q + head_off + (size_t)qg * D_ + c * 32 + hi * 8);

        float l_part = 0.f;
        f32x4 oacc[8] = {};
        int nkt = (qt >> 1) + 1;
        for (int kt = 0; kt < nkt; ++kt) {
            int k0 = kt * 128;
            __syncthreads();  // prior compute's LDS reads done
#pragma unroll
            for (int i = 0; i < 8; ++i) {
                int chunk = w * 8 + i;
                int r = chunk * 4 + (lane >> 4);
                int lc = (lane & 15) ^ (r & 15);
                async16(k + head_off + (size_t)(k0 + r) * D_ + lc * 8,
                        Ks + chunk * 512 + lane * 8);
            }
#pragma unroll
            for (int i = 0; i < 8; ++i) {
                int chunk = w * 8 + i;
                int d = chunk * 4 + (lane >> 4);
                int lc = (lane & 15) ^ (d & 15);
                async16(vt + vhead_off + (size_t)d * S_ + k0 + lc * 8,
                        Vs + chunk * 512 + lane * 8);
            }
            __syncthreads();  // staging visible

            if (k0 <= q0 + w * 16 + 15) {  // wave-uniform: skip fully-masked tiles
                // S^T = K * Q^T : C cols = q (lo), C rows = k (nt*16 + hi*4 + r)
                f32x4 sacc[8] = {};
#pragma unroll
                for (int c = 0; c < 4; ++c) {
#pragma unroll
                    for (int nt = 0; nt < 8; ++nt) {
                        int row = nt * 16 + lo;
                        int pc = (c * 4 + hi) ^ lo;
                        bf16x8 ak = *(const bf16x8*)(Ks + row * 128 + pc * 8);
                        sacc[nt] = __builtin_amdgcn_mfma_f32_16x16x32_bf16(ak, aq[c], sacc[nt], 0, 0, 0);
                    }
                }
                bool diag = (k0 + 127 > q0 + w * 16);
                bf16x4 pf[8];
#pragma unroll
                for (int nt = 0; nt < 8; ++nt) {
#pragma unroll
                    for (int r = 0; r < 4; ++r) {
                        float e = __expf(fminf(sacc[nt][r], 60.f));
                        if (diag) {
                            int kg = k0 + nt * 16 + hi * 4 + r;
                            if (kg > qg) e = 0.f;
                        }
                        l_part += e;
                        pf[nt][r] = (bf16_t)e;
                    }
                }
                // O^T[d][q] += V^T * P^T  (x16 MFMA: both operands' k = hi*4+j)
#pragma unroll
                for (int nt = 0; nt < 8; ++nt) {
                    int kkb = nt * 16 + hi * 4;
                    int c16 = kkb >> 3, rem = kkb & 7;
#pragma unroll
                    for (int dt = 0; dt < 8; ++dt) {
                        int d = dt * 16 + lo;
                        bf16x4 av = *(const bf16x4*)(Vs + d * 128 + (c16 ^ (d & 15)) * 8 + rem);
                        oacc[dt] = mfma16x16x16_bf16(av, pf[nt], oacc[dt]);
                    }
                }
            }
        }
        // epilogue: reduce l over hi-groups (q = lo is lane-resident), write O^T
        float l = l_part;
        l += __shfl_xor(l, 16);
        l += __shfl_xor(l, 32);
        float rl = 1.0f / l;
#pragma unroll
        for (int dt = 0; dt < 8; ++dt) {
            bf16x4 ov = { (bf16_t)(oacc[dt][0] * rl), (bf16_t)(oacc[dt][1] * rl),
                          (bf16_t)(oacc[dt][2] * rl), (bf16_t)(oacc[dt][3] * rl) };
            *(bf16x4*)(o + head_off + (size_t)qg * D_ + dt * 16 + hi * 4) = ov;
        }
    }
}

// ---------------- launch ----------------
extern "C" void kernel_launch(void* const* d_in, const int* in_sizes, int n_in,
                              void* d_out, int out_size, void* d_ws, size_t ws_size,
                              hipStream_t stream) {
    (void)in_sizes; (void)n_in; (void)out_size; (void)ws_size;
    const float* x  = (const float*)d_in[0];
    const float* Wq = (const float*)d_in[1];
    const float* Wk = (const float*)d_in[2];
    const float* Wv = (const float*)d_in[3];
    const float* Wo = (const float*)d_in[4];
    char* ws = (char*)d_ws;
    bf16_t* xb  = (bf16_t*)(ws);
    bf16_t* Wqb = (bf16_t*)(ws + 16777216);
    bf16_t* Wkb = (bf16_t*)(ws + 25165824);
    bf16_t* Wvb = (bf16_t*)(ws + 33554432);
    bf16_t* Wob = (bf16_t*)(ws + 41943040);
    bf16_t* qb  = (bf16_t*)(ws + 50331648);
    bf16_t* kb  = (bf16_t*)(ws + 67108864);
    bf16_t* vtb = (bf16_t*)(ws + 83886080);
    bf16_t* ob  = (bf16_t*)(ws + 100663296);
    float* out = (float*)d_out;

    f2b_multi<<<dim3(4096, 6), 256, 0, stream>>>(x, Wq, Wk, Wv, Wo, xb, Wqb, Wkb, Wvb, Wob);

    gemm_qkv<<<dim3(48, 32), 256, 0, stream>>>(xb, Wqb, Wkb, Wvb, qb, kb, vtb);

    rope_kernel<<<dim3((B_ * S_ * H_ * 8) / 256, 2), 256, 0, stream>>>(qb, kb);

    attn_kernel<<<dim3(16, B_ * H_), 256, 0, stream>>>(qb, kb, vtb, ob);

    gemm_bt_f32<<<dim3(D_ / 128, (B_ * S_) / 128), 256, 0, stream>>>(ob, Wob, out, B_ * S_, D_, D_);
}